// Round 3
// baseline (380.155 us; speedup 1.0000x reference)
//
#include <hip/hip_runtime.h>

// ---- problem constants ----
#define TT   512
#define BI   12
#define HH   50
#define BB   8     // batch per block
#define BTOT 2048
#define LOG2E 1.4426950408889634f

// R12 = R11 (368.7 us; VALUBusy 55%, MfmaUtil 23%) with the activation
// transcendental count cut 10 -> 7 and wave prioritization:
//  - common-denominator fusion (exact algebra): cm' = [cm*dI*dG +
//    (eG-1)*dF] / (dF*dI*dG) needs ONE rcp (was 3: fv, iv, gv);
//    h = (eC-1)/(dO*(1+eC)) needs ONE rcp (was 2: ov, tanh).
//    Trans/wave-step: 5 exp2 + 2 rcp = 7 (was 10) -> act issue phase
//    per SIMD ~320 -> ~224 cy. exp2 arg for tanh(cm) clamped at 60
//    (tanh(30)==1 in f32) so dO*dC <= 2^83: no inf*0 NaN possible;
//    gate pre-activations are structurally bounded (|pre| <= ~16).
//  - s_setprio(1) persistent on layer-1 waves (4 K-block MFMA chains,
//    they define barrier arrival; L0/L1 role diversity = the regime
//    where setprio pays; x-prefetch has 2 steps of slack).
// Carried from R11: scales folded into f16 weights (MFMA output IS the
// exp2 arg), fzero C-operand (no per-step acc zero-init), unified h0
// buffer (B0s = [h0 0-49 | x 50-61 | bias 62]; L1 reads kb0/kb1 from
// B0s, A zeroes cols 50-63; B1s = [h1 0-49 | bias 62]), LDS 8KB.
// Layout (verified R5-R11): row r = u*4+gate -> lane's f4 acc holds all 4
// gates of one (unit,batch); cell update in-register. B fragments in LDS
// order [k>>3][n][k&7]; ping-pong parities; one barrier/step; layers
// software-pipelined by one step (exact): step t: l0->h0[t], l1->h1[t-1].
// x prefetch 2 steps ahead (xhold), store at top-of-step.

typedef _Float16 half8 __attribute__((ext_vector_type(8)));
typedef float    f4    __attribute__((ext_vector_type(4)));

__device__ __forceinline__ float sigm_(float v) {
    return __builtin_amdgcn_rcpf(1.f + __builtin_amdgcn_exp2f(v * (-LOG2E)));
}
// lanes with (lane&15)<8 keep a0; lanes with (lane&15)>=8 take a1 from
// lane^8 (DPP row_ror:8 = 0x128, banks 2,3 -> bank_mask 0xC). One VALU op.
__device__ __forceinline__ float dppmerge_(float a0, float a1) {
    int r = __builtin_amdgcn_update_dpp(__builtin_bit_cast(int, a0),
                                        __builtin_bit_cast(int, a1),
                                        0x128, 0xF, 0xC, false);
    return __builtin_bit_cast(float, r);
}

__launch_bounds__(1024)
__global__ void lstm2_kernel(const float* __restrict__ x,
                             const float* __restrict__ w_ih0, const float* __restrict__ w_hh0,
                             const float* __restrict__ b_ih0, const float* __restrict__ b_hh0,
                             const float* __restrict__ w_ih1, const float* __restrict__ w_hh1,
                             const float* __restrict__ b_ih1, const float* __restrict__ b_hh1,
                             const float* __restrict__ w_out, const float* __restrict__ b_out,
                             float* __restrict__ out)
{
    const int tid   = threadIdx.x;
    const int wv    = tid >> 6;          // 0..15
    const int lane  = tid & 63;
    const int layer = wv >> 3;           // 0 or 1
    const int w8    = wv & 7;
    const int b0    = blockIdx.x * BB;
    // 13 M-tiles per layer over 8 waves: waves 0-4 take 2, waves 5-7 take 1.
    const int t0     = (w8 < 5) ? 2 * w8 : (5 + w8);
    const int ntiles = (w8 < 5) ? 2 : 1;

    // critical waves (layer 1: 4 K-block chains) win issue arbitration
    if (layer) __builtin_amdgcn_s_setprio(1);

    // K-space: B0s rows = [h0: 0-49 | x: 50-61 | bias(=1): 62 | pad: 63]
    //          B1s rows = [h1: 0-49 | unused: 50-61 | bias(=1): 62 | pad: 63]
    __shared__ __align__(16) _Float16 B0s[2][64 * 16];
    __shared__ __align__(16) _Float16 B1s[2][64 * 16];

    // ---- step-invariant A fragments (weights, fragment layout, pre-scaled) ----
    const int m = lane & 15;
    const int q = lane >> 4;
    half8 af[2][4];
    #pragma unroll
    for (int s = 0; s < 2; s++) {
        #pragma unroll
        for (int kb = 0; kb < 4; kb++) {
            #pragma unroll
            for (int j = 0; j < 8; j++) {
                float v = 0.f;
                if (s < ntiles && (layer == 1 || kb < 2)) {
                    const int T  = t0 + s;
                    const int u  = T * 4 + (m >> 2);
                    const int g  = m & 3;
                    const int kg = kb * 32 + q * 8 + j;
                    if (u < HH) {
                        const int r = g * HH + u;
                        if (layer == 0) {
                            if      (kg < 50)  v = w_hh0[r * HH + kg];
                            else if (kg < 62)  v = w_ih0[r * BI + (kg - 50)];
                            else if (kg == 62) v = b_ih0[r] + b_hh0[r];
                        } else {
                            if      (kg < 50)               v = w_ih1[r * HH + kg];
                            else if (kg >= 64 && kg < 114)  v = w_hh1[r * HH + (kg - 64)];
                            else if (kg == 126)             v = b_ih1[r] + b_hh1[r];
                        }
                        // fold activation input scale into the weight
                        v *= (g == 2) ? (2.f * LOG2E) : (-LOG2E);
                    }
                }
                af[s][kb][j] = (_Float16)v;
            }
        }
    }

    // ---- init LDS ----
    for (int i = tid; i < 2 * 64 * 16; i += 1024) {
        (&B0s[0][0])[i] = (_Float16)0.f;
        (&B1s[0][0])[i] = (_Float16)0.f;
    }
    __syncthreads();
    if (tid < 16) {                       // bias (ones) row 62, both parities
        B0s[0][7 * 128 + tid * 8 + 6] = (_Float16)1.f;
        B0s[1][7 * 128 + tid * 8 + 6] = (_Float16)1.f;
        B1s[0][7 * 128 + tid * 8 + 6] = (_Float16)1.f;
        B1s[1][7 * 128 + tid * 8 + 6] = (_Float16)1.f;
    }
    const int xb = tid / 12, xi = tid - xb * 12;           // loop-invariant
    const int xrow = 50 + xi;
    const int xoff = (xrow >> 3) * 128 + xb * 8 + (xrow & 7);
    const size_t xbase = ((size_t)(b0 + xb) * TT) * BI + xi;
    if (tid < 96)                          // x[0] -> parity 0
        B0s[0][xoff] = (_Float16)x[xbase];
    __syncthreads();

    // ---- merged update role: lane owns (u_m, bcol) ----
    const int n16  = lane & 15;
    const int slot = n16 >> 3;            // 0: own acc0; 1: partner's acc1
    const int bcol = n16 & 7;
    const int u_m  = (t0 + slot) * 4 + q;
    const bool wvalid = (u_m < HH) && (slot == 0 || ntiles == 2);
    float cm = 0.f;                        // cell state for (u_m, bcol)

    // ---- per-parity pointers (constant-indexed -> folded at compile time) ----
    const _Float16* rd0[2] = { &B0s[0][0] + lane * 8, &B0s[1][0] + lane * 8 };
    const _Float16* rd1[2] = { &B1s[0][0] + lane * 8, &B1s[1][0] + lane * 8 };
    const int offA = (u_m >> 3) * 128 + bcol * 8 + (u_m & 7);   // h row = u_m
    _Float16* wAp[2] = { (layer ? &B1s[0][0] : &B0s[0][0]) + offA,
                         (layer ? &B1s[1][0] : &B0s[1][0]) + offA };
    _Float16* xdp[2] = { &B0s[0][0] + xoff, &B0s[1][0] + xoff };

    const f4 fzero = {0.f, 0.f, 0.f, 0.f};

    // x stream, 2-step-ahead: xhold carries x[t+1] across a full step.
    const float* xq = x + xbase + BI;     // points at x[1]
    float xhold = 0.f;
    if (tid < 96) xhold = *xq;            // preload x[1]
    xq += BI;                             // points at x[2]

// One timestep at compile-time parity P. DOL0/DOL1: layer activity
// (peel boundaries). DOST: store xhold (=x[t+1]) into parity 1-P.
// DOLD: issue load of x[t+2] (consumed next step).
// Act math (exact algebra; am[] = MFMA out = pre-scaled exp2 args):
//   eI=2^am0, eF=2^am1, eG=2^am2, eO=2^am3 (i,f,o args = -log2e*pre;
//   g arg = 2log2e*pre). fv=1/dF, iv*gv=(eG-1)/(dI*dG) ->
//   cm' = [cm*dI*dG + (eG-1)*dF] * rcp(dF*dI*dG)          (1 rcp)
//   h   = (eC-1) * rcp(dO*(1+eC)), eC=2^min(2log2e*cm',60) (1 rcp)
#define STEP(P, DOL0, DOL1, DOST, DOLD)                                       \
  {                                                                           \
    float xnew = 0.f;                                                         \
    if ((DOLD) && tid < 96) xnew = *xq;                                       \
    if ((DOST) && tid < 96) *xdp[1 - (P)] = (_Float16)xhold;                  \
    if ((layer == 0) ? (DOL0) : (DOL1)) {                                     \
      const half8 bf0 = *(const half8*)(rd0[P]);                              \
      const half8 bf1 = *(const half8*)(rd0[P] + 512);                        \
      f4 acc0, acc1 = fzero;                                                  \
      if (layer == 0) {                                                       \
        acc0 = __builtin_amdgcn_mfma_f32_16x16x32_f16(af[0][0], bf0, fzero, 0, 0, 0); \
        acc0 = __builtin_amdgcn_mfma_f32_16x16x32_f16(af[0][1], bf1, acc0, 0, 0, 0);  \
        if (ntiles > 1) {                                                     \
          acc1 = __builtin_amdgcn_mfma_f32_16x16x32_f16(af[1][0], bf0, fzero, 0, 0, 0); \
          acc1 = __builtin_amdgcn_mfma_f32_16x16x32_f16(af[1][1], bf1, acc1, 0, 0, 0);  \
        }                                                                     \
      } else {                                                                \
        const half8 bf2 = *(const half8*)(rd1[P]);                            \
        const half8 bf3 = *(const half8*)(rd1[P] + 512);                      \
        f4 a0  = __builtin_amdgcn_mfma_f32_16x16x32_f16(af[0][0], bf0, fzero, 0, 0, 0); \
        f4 a0b = __builtin_amdgcn_mfma_f32_16x16x32_f16(af[0][1], bf1, fzero, 0, 0, 0); \
        a0  = __builtin_amdgcn_mfma_f32_16x16x32_f16(af[0][2], bf2, a0,  0, 0, 0);      \
        a0b = __builtin_amdgcn_mfma_f32_16x16x32_f16(af[0][3], bf3, a0b, 0, 0, 0);      \
        acc0 = a0 + a0b;                                                      \
        if (ntiles > 1) {                                                     \
          f4 a1  = __builtin_amdgcn_mfma_f32_16x16x32_f16(af[1][0], bf0, fzero, 0, 0, 0); \
          f4 a1b = __builtin_amdgcn_mfma_f32_16x16x32_f16(af[1][1], bf1, fzero, 0, 0, 0); \
          a1  = __builtin_amdgcn_mfma_f32_16x16x32_f16(af[1][2], bf2, a1,  0, 0, 0);      \
          a1b = __builtin_amdgcn_mfma_f32_16x16x32_f16(af[1][3], bf3, a1b, 0, 0, 0);      \
          acc1 = a1 + a1b;                                                    \
        }                                                                     \
      }                                                                       \
      f4 am;                                                                  \
      _Pragma("unroll")                                                       \
      for (int i = 0; i < 4; i++) am[i] = dppmerge_(acc0[i], acc1[i]);        \
      const float eI = __builtin_amdgcn_exp2f(am[0]);                         \
      const float eF = __builtin_amdgcn_exp2f(am[1]);                         \
      const float eG = __builtin_amdgcn_exp2f(am[2]);                         \
      const float eO = __builtin_amdgcn_exp2f(am[3]);                         \
      const float dI = 1.f + eI, dF = 1.f + eF;                               \
      const float dG = 1.f + eG, dO = 1.f + eO;                               \
      const float pIG = dI * dG;                                             \
      const float num = __builtin_fmaf(cm, pIG, (eG - 1.f) * dF);             \
      cm = num * __builtin_amdgcn_rcpf(dF * pIG);                             \
      const float uu = fminf(cm * (2.f * LOG2E), 60.f);                       \
      const float eC = __builtin_amdgcn_exp2f(uu);                            \
      const float h  = (eC - 1.f) * __builtin_amdgcn_rcpf(dO * (1.f + eC));   \
      if (wvalid) *wAp[1 - (P)] = (_Float16)h;                                \
    }                                                                         \
    if (DOLD) { xhold = xnew; xq += BI; }                                     \
    __syncthreads();                                                          \
  }

    STEP(0, 1, 0, 1, 1)                   // t = 0   (l0 only; store x[1], load x[2])
    STEP(1, 1, 1, 1, 1)                   // t = 1
    #pragma unroll 1
    for (int it = 0; it < 254; ++it) {    // t = 2 .. 509
        STEP(0, 1, 1, 1, 1)
        STEP(1, 1, 1, 1, 1)
    }
    STEP(0, 1, 1, 1, 0)                   // t = 510 (store x[511], no more loads)
    STEP(1, 1, 1, 0, 0)                   // t = 511
    STEP(0, 0, 1, 0, 0)                   // t = 512 (l1 only)
#undef STEP

    // ---- epilogue: sigmoid(h1[TT-1] . w_out + b_out); h1[TT-1] in parity 1 ----
    if (tid < BB) {
        float s = b_out[0];
        #pragma unroll
        for (int u = 0; u < HH; u++) {
            s += w_out[u] * (float)B1s[1][(u >> 3) * 128 + tid * 8 + (u & 7)];
        }
        out[b0 + tid] = sigm_(s);
    }
}

extern "C" void kernel_launch(void* const* d_in, const int* in_sizes, int n_in,
                              void* d_out, int out_size, void* d_ws, size_t ws_size,
                              hipStream_t stream) {
    const float* x     = (const float*)d_in[0];
    const float* w_ih0 = (const float*)d_in[1];
    const float* w_hh0 = (const float*)d_in[2];
    const float* b_ih0 = (const float*)d_in[3];
    const float* b_hh0 = (const float*)d_in[4];
    const float* w_ih1 = (const float*)d_in[5];
    const float* w_hh1 = (const float*)d_in[6];
    const float* b_ih1 = (const float*)d_in[7];
    const float* b_hh1 = (const float*)d_in[8];
    const float* w_out = (const float*)d_in[9];
    const float* b_out = (const float*)d_in[10];
    float* out = (float*)d_out;

    dim3 grid(BTOT / BB);   // 256 blocks -> 1 per CU
    dim3 block(1024);       // 16 waves: 8 layer-0 + 8 layer-1
    lstm2_kernel<<<grid, block, 0, stream>>>(x, w_ih0, w_hh0, b_ih0, b_hh0,
                                             w_ih1, w_hh1, b_ih1, b_hh1,
                                             w_out, b_out, out);
}

// Round 4
// 373.632 us; speedup vs baseline: 1.0175x; 1.0175x over previous
//
#include <hip/hip_runtime.h>

// ---- problem constants ----
#define TT   512
#define BI   12
#define HH   50
#define BB   8     // batch per block
#define BTOT 2048
#define LOG2E 1.4426950408889634f

// R13 = R12 (dispatch ~324 us; VALUBusy 52, MfmaUtil 23 -> ~25% bubble)
// with the barrier vmcnt-drain stall removed and setprio reverted:
//  - STEP barrier: __syncthreads() (which compiles to s_waitcnt vmcnt(0)
//    lgkmcnt(0) + s_barrier, m97 evidence) -> explicit
//    `s_waitcnt lgkmcnt(0)` + raw s_barrier. LDS writes (h, x-store)
//    still drain before the barrier (all cross-wave traffic is LDS), but
//    the streaming x global-load now stays IN FLIGHT across the barrier;
//    its auto-waitcnt lands at consumption one full step later. This
//    restores the 2-step xhold prefetch that the implicit vmcnt(0) was
//    defeating every step (~900cy HBM miss amortized ~300cy/step = the
//    observed bubble).
//  - setprio(1) on L1 reverted: lockstep single-barrier structure is the
//    regime where setprio measured null-to-negative (m190); suspected of
//    cancelling R12's trans-fusion win.
// Carried: trans fusion (5 exp2 + 2 rcp, common-denominator cell update,
// exp2-arg clamp 60), scales folded into f16 weights, fzero C-operand,
// unified h0 buffer (B0s=[h0 0-49|x 50-61|bias 62], B1s=[h1 0-49|bias 62],
// LDS 8KB), 2-step xhold prefetch, store at top-of-step.
// Layout (verified R5-R12): row r = u*4+gate -> lane's f4 acc holds all 4
// gates of one (unit,batch); cell update in-register. B fragments in LDS
// order [k>>3][n][k&7]; ping-pong parities; one barrier/step; layers
// software-pipelined by one step (exact): step t: l0->h0[t], l1->h1[t-1].

typedef _Float16 half8 __attribute__((ext_vector_type(8)));
typedef float    f4    __attribute__((ext_vector_type(4)));

__device__ __forceinline__ float sigm_(float v) {
    return __builtin_amdgcn_rcpf(1.f + __builtin_amdgcn_exp2f(v * (-LOG2E)));
}
// lanes with (lane&15)<8 keep a0; lanes with (lane&15)>=8 take a1 from
// lane^8 (DPP row_ror:8 = 0x128, banks 2,3 -> bank_mask 0xC). One VALU op.
__device__ __forceinline__ float dppmerge_(float a0, float a1) {
    int r = __builtin_amdgcn_update_dpp(__builtin_bit_cast(int, a0),
                                        __builtin_bit_cast(int, a1),
                                        0x128, 0xF, 0xC, false);
    return __builtin_bit_cast(float, r);
}

__launch_bounds__(1024)
__global__ void lstm2_kernel(const float* __restrict__ x,
                             const float* __restrict__ w_ih0, const float* __restrict__ w_hh0,
                             const float* __restrict__ b_ih0, const float* __restrict__ b_hh0,
                             const float* __restrict__ w_ih1, const float* __restrict__ w_hh1,
                             const float* __restrict__ b_ih1, const float* __restrict__ b_hh1,
                             const float* __restrict__ w_out, const float* __restrict__ b_out,
                             float* __restrict__ out)
{
    const int tid   = threadIdx.x;
    const int wv    = tid >> 6;          // 0..15
    const int lane  = tid & 63;
    const int layer = wv >> 3;           // 0 or 1
    const int w8    = wv & 7;
    const int b0    = blockIdx.x * BB;
    // 13 M-tiles per layer over 8 waves: waves 0-4 take 2, waves 5-7 take 1.
    const int t0     = (w8 < 5) ? 2 * w8 : (5 + w8);
    const int ntiles = (w8 < 5) ? 2 : 1;

    // K-space: B0s rows = [h0: 0-49 | x: 50-61 | bias(=1): 62 | pad: 63]
    //          B1s rows = [h1: 0-49 | unused: 50-61 | bias(=1): 62 | pad: 63]
    __shared__ __align__(16) _Float16 B0s[2][64 * 16];
    __shared__ __align__(16) _Float16 B1s[2][64 * 16];

    // ---- step-invariant A fragments (weights, fragment layout, pre-scaled) ----
    const int m = lane & 15;
    const int q = lane >> 4;
    half8 af[2][4];
    #pragma unroll
    for (int s = 0; s < 2; s++) {
        #pragma unroll
        for (int kb = 0; kb < 4; kb++) {
            #pragma unroll
            for (int j = 0; j < 8; j++) {
                float v = 0.f;
                if (s < ntiles && (layer == 1 || kb < 2)) {
                    const int T  = t0 + s;
                    const int u  = T * 4 + (m >> 2);
                    const int g  = m & 3;
                    const int kg = kb * 32 + q * 8 + j;
                    if (u < HH) {
                        const int r = g * HH + u;
                        if (layer == 0) {
                            if      (kg < 50)  v = w_hh0[r * HH + kg];
                            else if (kg < 62)  v = w_ih0[r * BI + (kg - 50)];
                            else if (kg == 62) v = b_ih0[r] + b_hh0[r];
                        } else {
                            if      (kg < 50)               v = w_ih1[r * HH + kg];
                            else if (kg >= 64 && kg < 114)  v = w_hh1[r * HH + (kg - 64)];
                            else if (kg == 126)             v = b_ih1[r] + b_hh1[r];
                        }
                        // fold activation input scale into the weight
                        v *= (g == 2) ? (2.f * LOG2E) : (-LOG2E);
                    }
                }
                af[s][kb][j] = (_Float16)v;
            }
        }
    }

    // ---- init LDS ----
    for (int i = tid; i < 2 * 64 * 16; i += 1024) {
        (&B0s[0][0])[i] = (_Float16)0.f;
        (&B1s[0][0])[i] = (_Float16)0.f;
    }
    __syncthreads();
    if (tid < 16) {                       // bias (ones) row 62, both parities
        B0s[0][7 * 128 + tid * 8 + 6] = (_Float16)1.f;
        B0s[1][7 * 128 + tid * 8 + 6] = (_Float16)1.f;
        B1s[0][7 * 128 + tid * 8 + 6] = (_Float16)1.f;
        B1s[1][7 * 128 + tid * 8 + 6] = (_Float16)1.f;
    }
    const int xb = tid / 12, xi = tid - xb * 12;           // loop-invariant
    const int xrow = 50 + xi;
    const int xoff = (xrow >> 3) * 128 + xb * 8 + (xrow & 7);
    const size_t xbase = ((size_t)(b0 + xb) * TT) * BI + xi;
    if (tid < 96)                          // x[0] -> parity 0
        B0s[0][xoff] = (_Float16)x[xbase];
    __syncthreads();

    // ---- merged update role: lane owns (u_m, bcol) ----
    const int n16  = lane & 15;
    const int slot = n16 >> 3;            // 0: own acc0; 1: partner's acc1
    const int bcol = n16 & 7;
    const int u_m  = (t0 + slot) * 4 + q;
    const bool wvalid = (u_m < HH) && (slot == 0 || ntiles == 2);
    float cm = 0.f;                        // cell state for (u_m, bcol)

    // ---- per-parity pointers (constant-indexed -> folded at compile time) ----
    const _Float16* rd0[2] = { &B0s[0][0] + lane * 8, &B0s[1][0] + lane * 8 };
    const _Float16* rd1[2] = { &B1s[0][0] + lane * 8, &B1s[1][0] + lane * 8 };
    const int offA = (u_m >> 3) * 128 + bcol * 8 + (u_m & 7);   // h row = u_m
    _Float16* wAp[2] = { (layer ? &B1s[0][0] : &B0s[0][0]) + offA,
                         (layer ? &B1s[1][0] : &B0s[1][0]) + offA };
    _Float16* xdp[2] = { &B0s[0][0] + xoff, &B0s[1][0] + xoff };

    const f4 fzero = {0.f, 0.f, 0.f, 0.f};

    // x stream, 2-step-ahead: xhold carries x[t+1] across a full step.
    const float* xq = x + xbase + BI;     // points at x[1]
    float xhold = 0.f;
    if (tid < 96) xhold = *xq;            // preload x[1]
    xq += BI;                             // points at x[2]

// Barrier: LDS-only drain + raw s_barrier (NO vmcnt drain). All
// cross-wave dependencies are LDS; the x global load stays in flight
// across the barrier and its auto-waitcnt lands at consumption next step.
#define BARRIER()                                                             \
    asm volatile("s_waitcnt lgkmcnt(0)" ::: "memory");                        \
    __builtin_amdgcn_s_barrier();                                             \
    asm volatile("" ::: "memory");

// One timestep at compile-time parity P. DOL0/DOL1: layer activity
// (peel boundaries). DOST: store xhold (=x[t+1]) into parity 1-P.
// DOLD: issue load of x[t+2] (consumed next step).
// Act math (exact algebra; am[] = MFMA out = pre-scaled exp2 args):
//   eI=2^am0, eF=2^am1, eG=2^am2, eO=2^am3 (i,f,o args = -log2e*pre;
//   g arg = 2log2e*pre). fv=1/dF, iv*gv=(eG-1)/(dI*dG) ->
//   cm' = [cm*dI*dG + (eG-1)*dF] * rcp(dF*dI*dG)          (1 rcp)
//   h   = (eC-1) * rcp(dO*(1+eC)), eC=2^min(2log2e*cm',60) (1 rcp)
#define STEP(P, DOL0, DOL1, DOST, DOLD)                                       \
  {                                                                           \
    float xnew = 0.f;                                                         \
    if ((DOLD) && tid < 96) xnew = *xq;                                       \
    if ((DOST) && tid < 96) *xdp[1 - (P)] = (_Float16)xhold;                  \
    if ((layer == 0) ? (DOL0) : (DOL1)) {                                     \
      const half8 bf0 = *(const half8*)(rd0[P]);                              \
      const half8 bf1 = *(const half8*)(rd0[P] + 512);                        \
      f4 acc0, acc1 = fzero;                                                  \
      if (layer == 0) {                                                       \
        acc0 = __builtin_amdgcn_mfma_f32_16x16x32_f16(af[0][0], bf0, fzero, 0, 0, 0); \
        acc0 = __builtin_amdgcn_mfma_f32_16x16x32_f16(af[0][1], bf1, acc0, 0, 0, 0);  \
        if (ntiles > 1) {                                                     \
          acc1 = __builtin_amdgcn_mfma_f32_16x16x32_f16(af[1][0], bf0, fzero, 0, 0, 0); \
          acc1 = __builtin_amdgcn_mfma_f32_16x16x32_f16(af[1][1], bf1, acc1, 0, 0, 0);  \
        }                                                                     \
      } else {                                                                \
        const half8 bf2 = *(const half8*)(rd1[P]);                            \
        const half8 bf3 = *(const half8*)(rd1[P] + 512);                      \
        f4 a0  = __builtin_amdgcn_mfma_f32_16x16x32_f16(af[0][0], bf0, fzero, 0, 0, 0); \
        f4 a0b = __builtin_amdgcn_mfma_f32_16x16x32_f16(af[0][1], bf1, fzero, 0, 0, 0); \
        a0  = __builtin_amdgcn_mfma_f32_16x16x32_f16(af[0][2], bf2, a0,  0, 0, 0);      \
        a0b = __builtin_amdgcn_mfma_f32_16x16x32_f16(af[0][3], bf3, a0b, 0, 0, 0);      \
        acc0 = a0 + a0b;                                                      \
        if (ntiles > 1) {                                                     \
          f4 a1  = __builtin_amdgcn_mfma_f32_16x16x32_f16(af[1][0], bf0, fzero, 0, 0, 0); \
          f4 a1b = __builtin_amdgcn_mfma_f32_16x16x32_f16(af[1][1], bf1, fzero, 0, 0, 0); \
          a1  = __builtin_amdgcn_mfma_f32_16x16x32_f16(af[1][2], bf2, a1,  0, 0, 0);      \
          a1b = __builtin_amdgcn_mfma_f32_16x16x32_f16(af[1][3], bf3, a1b, 0, 0, 0);      \
          acc1 = a1 + a1b;                                                    \
        }                                                                     \
      }                                                                       \
      f4 am;                                                                  \
      _Pragma("unroll")                                                       \
      for (int i = 0; i < 4; i++) am[i] = dppmerge_(acc0[i], acc1[i]);        \
      const float eI = __builtin_amdgcn_exp2f(am[0]);                         \
      const float eF = __builtin_amdgcn_exp2f(am[1]);                         \
      const float eG = __builtin_amdgcn_exp2f(am[2]);                         \
      const float eO = __builtin_amdgcn_exp2f(am[3]);                         \
      const float dI = 1.f + eI, dF = 1.f + eF;                               \
      const float dG = 1.f + eG, dO = 1.f + eO;                               \
      const float pIG = dI * dG;                                              \
      const float num = __builtin_fmaf(cm, pIG, (eG - 1.f) * dF);             \
      cm = num * __builtin_amdgcn_rcpf(dF * pIG);                             \
      const float uu = fminf(cm * (2.f * LOG2E), 60.f);                       \
      const float eC = __builtin_amdgcn_exp2f(uu);                            \
      const float h  = (eC - 1.f) * __builtin_amdgcn_rcpf(dO * (1.f + eC));   \
      if (wvalid) *wAp[1 - (P)] = (_Float16)h;                                \
    }                                                                         \
    if (DOLD) { xhold = xnew; xq += BI; }                                     \
    BARRIER()                                                                 \
  }

    STEP(0, 1, 0, 1, 1)                   // t = 0   (l0 only; store x[1], load x[2])
    STEP(1, 1, 1, 1, 1)                   // t = 1
    #pragma unroll 1
    for (int it = 0; it < 254; ++it) {    // t = 2 .. 509
        STEP(0, 1, 1, 1, 1)
        STEP(1, 1, 1, 1, 1)
    }
    STEP(0, 1, 1, 1, 0)                   // t = 510 (store x[511], no more loads)
    STEP(1, 1, 1, 0, 0)                   // t = 511
    STEP(0, 0, 1, 0, 0)                   // t = 512 (l1 only)
#undef STEP
#undef BARRIER

    // ---- epilogue: sigmoid(h1[TT-1] . w_out + b_out); h1[TT-1] in parity 1 ----
    if (tid < BB) {
        float s = b_out[0];
        #pragma unroll
        for (int u = 0; u < HH; u++) {
            s += w_out[u] * (float)B1s[1][(u >> 3) * 128 + tid * 8 + (u & 7)];
        }
        out[b0 + tid] = sigm_(s);
    }
}

extern "C" void kernel_launch(void* const* d_in, const int* in_sizes, int n_in,
                              void* d_out, int out_size, void* d_ws, size_t ws_size,
                              hipStream_t stream) {
    const float* x     = (const float*)d_in[0];
    const float* w_ih0 = (const float*)d_in[1];
    const float* w_hh0 = (const float*)d_in[2];
    const float* b_ih0 = (const float*)d_in[3];
    const float* b_hh0 = (const float*)d_in[4];
    const float* w_ih1 = (const float*)d_in[5];
    const float* w_hh1 = (const float*)d_in[6];
    const float* b_ih1 = (const float*)d_in[7];
    const float* b_hh1 = (const float*)d_in[8];
    const float* w_out = (const float*)d_in[9];
    const float* b_out = (const float*)d_in[10];
    float* out = (float*)d_out;

    dim3 grid(BTOT / BB);   // 256 blocks -> 1 per CU
    dim3 block(1024);       // 16 waves: 8 layer-0 + 8 layer-1
    lstm2_kernel<<<grid, block, 0, stream>>>(x, w_ih0, w_hh0, b_ih0, b_hh0,
                                             w_ih1, w_hh1, b_ih1, b_hh1,
                                             w_out, b_out, out);
}